// Round 6
// baseline (598.327 us; speedup 1.0000x reference)
//
#include <hip/hip_runtime.h>

#define NHEADS 16
#define DKV 128
#define BB 2
#define SS 2048
#define DD 2048

typedef __attribute__((ext_vector_type(8))) short bf16x8;
typedef __attribute__((ext_vector_type(4))) short bf16x4;
typedef __attribute__((ext_vector_type(4))) float f32x4;

// scale 1/sqrt(128) * log2(e)  (we use exp2 instead of exp)
#define QSCL 0.12752775f

__device__ __forceinline__ short f2bf(float x) {
  unsigned u = __builtin_bit_cast(unsigned, x);
  unsigned r = (u + 0x7fffu + ((u >> 16) & 1u)) >> 16;  // RTNE
  return (short)(unsigned short)r;
}
__device__ __forceinline__ float bf2f(short s) {
  unsigned u = ((unsigned)(unsigned short)s) << 16;
  return __builtin_bit_cast(float, u);
}
__device__ __forceinline__ unsigned pk2bf(float a, float b) {
#if __has_builtin(__builtin_amdgcn_cvt_pk_bf16_f32)
  typedef __attribute__((ext_vector_type(2))) __bf16 bf2_t;
  bf2_t r = __builtin_amdgcn_cvt_pk_bf16_f32(a, b);
  return __builtin_bit_cast(unsigned, r);
#else
  unsigned ua = __builtin_bit_cast(unsigned, a);
  unsigned ub = __builtin_bit_cast(unsigned, b);
  return ((ua + 0x8000u) >> 16) | ((ub + 0x8000u) & 0xffff0000u);
#endif
}
__device__ __forceinline__ float exp2fast(float x) {
#if __has_builtin(__builtin_amdgcn_exp2f)
  return __builtin_amdgcn_exp2f(x);
#else
  return exp2f(x);
#endif
}

// async global->LDS, 16B/lane; lds dst = wave-uniform base + lane*16
__device__ __forceinline__ void async16(const void* g, void* l) {
  __builtin_amdgcn_global_load_lds(
      (__attribute__((address_space(1))) void*)g,
      (__attribute__((address_space(3))) void*)l, 16, 0, 0);
}
__device__ __forceinline__ void wait_vm0() {
  asm volatile("s_waitcnt vmcnt(0)" ::: "memory");
}

// ============ weight transpose: W[K][N] fp32 -> Wt[N][K] bf16 * scale =====
__global__ __launch_bounds__(256) void transpose_w(
    const float* __restrict__ W, short* __restrict__ Wt, int K, int N,
    float scale) {
  __shared__ float T[32][33];
  const int nt = blockIdx.x * 32;
  const int kt = blockIdx.y * 32;
  const int tx = threadIdx.x & 31;
  const int ty = threadIdx.x >> 5;
#pragma unroll
  for (int i = 0; i < 4; ++i)
    T[ty + i * 8][tx] = W[(size_t)(kt + ty + i * 8) * N + nt + tx];
  __syncthreads();
#pragma unroll
  for (int i = 0; i < 4; ++i)
    Wt[(size_t)(nt + ty + i * 8) * K + kt + tx] = f2bf(T[tx][ty + i * 8] * scale);
}

// ============ mask bool -> float bias (log2-domain; -1e30 ~ -inf) =========
__global__ void mask_bias(const unsigned char* __restrict__ m,
                          float* __restrict__ mb) {
  int i = blockIdx.x * 256 + threadIdx.x;
  mb[i] = m[i] ? -1e30f : 0.0f;
}

// ============ MFMA GEMM with async staging ================================
// C[M,N] = A[M,K] @ Bt[N,K]^T. AMODE 0: A fp32 (VGPR convert). 1: A bf16.
// cmode 0: fp32 + bias*bscale. 1: bf16 + bias*bscale. 2: fp32 partial.
template <int AMODE>
__global__ __launch_bounds__(256) void gemm_as(
    const void* __restrict__ Ap, const short* __restrict__ Bt,
    const float* __restrict__ bias, void* __restrict__ Cp,
    int M, int N, int K, int KC, int cmode, float bscale) {
  __shared__ __align__(16) short As[128 * 32];
  __shared__ __align__(16) short Bs[128 * 32];
  const int tid = threadIdx.x;
  const int bm = blockIdx.y * 128;
  const int bn = blockIdx.x * 128;
  const int kz = blockIdx.z;
  const int w = tid >> 6, lane = tid & 63;
  const int lm = lane & 15, q4 = lane >> 4;
  const int m0 = (w & 1) * 64, n0 = (w >> 1) * 64;

  f32x4 acc[4][4];
#pragma unroll
  for (int mi = 0; mi < 4; ++mi)
#pragma unroll
    for (int ni = 0; ni < 4; ++ni) acc[mi][ni] = (f32x4){0.f, 0.f, 0.f, 0.f};

  const int kbeg = kz * KC;
  const int kend = kbeg + KC;

  for (int k0 = kbeg; k0 < kend; k0 += 32) {
    __syncthreads();
    if (AMODE == 1) {
      const short* Ab = (const short*)Ap;
#pragma unroll
      for (int i = 0; i < 2; ++i) {
        int rA = (w * 2 + i) * 16 + (lane >> 2);
        int cA = (lane & 3) ^ (rA & 3);
        async16(Ab + (size_t)(bm + rA) * K + k0 + cA * 8, &As[(w * 2 + i) * 512]);
      }
    } else {
      const float* Af = (const float*)Ap;
      float4 av[4];
#pragma unroll
      for (int i = 0; i < 4; ++i) {
        int qd = tid + i * 256;
        int r = qd >> 3, cq = qd & 7;
        av[i] = *(const float4*)(Af + (size_t)(bm + r) * K + k0 + cq * 4);
      }
#pragma unroll
      for (int i = 0; i < 4; ++i) {
        int qd = tid + i * 256;
        int r = qd >> 3, cq = qd & 7;
        int ch = cq >> 1, hf = cq & 1;
        int pc = ch ^ (r & 3);
        bf16x4 t = {f2bf(av[i].x), f2bf(av[i].y), f2bf(av[i].z), f2bf(av[i].w)};
        *(bf16x4*)&As[r * 32 + pc * 8 + hf * 4] = t;
      }
    }
#pragma unroll
    for (int i = 0; i < 2; ++i) {
      int rB = (w * 2 + i) * 16 + (lane >> 2);
      int cB = (lane & 3) ^ (rB & 3);
      async16(Bt + (size_t)(bn + rB) * K + k0 + cB * 8, &Bs[(w * 2 + i) * 512]);
    }
    __syncthreads();

    bf16x8 af[4], bf[4];
#pragma unroll
    for (int mi = 0; mi < 4; ++mi)
      af[mi] = *(const bf16x8*)&As[(m0 + mi * 16 + lm) * 32 + ((q4 ^ (lm & 3)) * 8)];
#pragma unroll
    for (int ni = 0; ni < 4; ++ni)
      bf[ni] = *(const bf16x8*)&Bs[(n0 + ni * 16 + lm) * 32 + ((q4 ^ (lm & 3)) * 8)];
#pragma unroll
    for (int mi = 0; mi < 4; ++mi)
#pragma unroll
      for (int ni = 0; ni < 4; ++ni)
        acc[mi][ni] = __builtin_amdgcn_mfma_f32_16x16x32_bf16(
            af[mi], bf[ni], acc[mi][ni], 0, 0, 0);
  }

  if (cmode == 2) {
    float* Cf = (float*)Cp + (size_t)kz * M * N;
#pragma unroll
    for (int mi = 0; mi < 4; ++mi)
#pragma unroll
      for (int ni = 0; ni < 4; ++ni)
#pragma unroll
        for (int reg = 0; reg < 4; ++reg)
          Cf[(size_t)(bm + m0 + mi * 16 + q4 * 4 + reg) * N +
             (bn + n0 + ni * 16 + lm)] = acc[mi][ni][reg];
  } else {
#pragma unroll
    for (int mi = 0; mi < 4; ++mi)
#pragma unroll
      for (int ni = 0; ni < 4; ++ni)
#pragma unroll
        for (int reg = 0; reg < 4; ++reg) {
          int rowg = bm + m0 + mi * 16 + q4 * 4 + reg;
          int colg = bn + n0 + ni * 16 + lm;
          float val = acc[mi][ni][reg] + bias[colg] * bscale;
          if (cmode == 0)
            ((float*)Cp)[(size_t)rowg * N + colg] = val;
          else
            ((short*)Cp)[(size_t)rowg * N + colg] = f2bf(val);
        }
  }
}

// ============ KV reduce + bias + K-RoPE + V-transpose (32 rows/block) =====
#define SPLITK 4
__global__ __launch_bounds__(256) void kv_reduce(
    const float* __restrict__ kpart, const float* __restrict__ vpart,
    const float* __restrict__ bk, const float* __restrict__ bv,
    short* __restrict__ kp, short* __restrict__ vtb) {
  __shared__ float Kt[32][128];
  __shared__ short Vl[128][36];
  const int tid = threadIdx.x;
  const int r0 = blockIdx.x * 32;
#pragma unroll
  for (int i = 0; i < 16; ++i) {
    int e = tid + i * 256;
    int r = e >> 7, c = e & 127;
    float sk = 0.f, sv = 0.f;
#pragma unroll
    for (int z = 0; z < SPLITK; ++z) {
      sk += kpart[((size_t)z * 4096 + r0 + r) * 128 + c];
      sv += vpart[((size_t)z * 4096 + r0 + r) * 128 + c];
    }
    Kt[r][c] = sk + bk[c];
    Vl[c][r] = f2bf(sv + bv[c]);
  }
  __syncthreads();
#pragma unroll
  for (int i = 0; i < 8; ++i) {
    int e = tid + i * 256;
    int r = e >> 6, d = e & 63;
    float x1 = Kt[r][d], x2 = Kt[r][d + 64];
    float s = (float)((r0 + r) & (SS - 1));
    float ang = s * exp2fast((float)d * (-13.287712379549449f / 64.0f));
    float sn, cs;
    __sincosf(ang, &sn, &cs);
    kp[(size_t)(r0 + r) * 128 + d] = f2bf(x1 * cs - x2 * sn);
    kp[(size_t)(r0 + r) * 128 + d + 64] = f2bf(x1 * sn + x2 * cs);
  }
  const int b = r0 >> 11;
  const int j = tid >> 1, soff = (tid & 1) * 16;
  short* dst = vtb + ((size_t)b * 128 + j) * SS + (r0 & (SS - 1)) + soff;
#pragma unroll
  for (int t = 0; t < 2; ++t) {
    bf16x8 tmp;
#pragma unroll
    for (int u = 0; u < 8; ++u) tmp[u] = Vl[j][soff + t * 8 + u];
    *(bf16x8*)(dst + t * 8) = tmp;
  }
}

// ============ RoPE on projected Q (bf16, in place, scale-preserving) ======
__global__ __launch_bounds__(256) void rope_q(short* __restrict__ qp) {
  int idx = blockIdx.x * 256 + threadIdx.x;
  int j8 = idx & 7;
  int h = (idx >> 3) & (NHEADS - 1);
  int s = (idx >> 7) & (SS - 1);
  int b = idx >> 18;
  short* base = qp + (((size_t)b * SS + s) * NHEADS + h) * DKV + j8 * 8;
  bf16x8 x1 = *(bf16x8*)base;
  bf16x8 x2 = *(bf16x8*)(base + 64);
  bf16x8 y1, y2;
#pragma unroll
  for (int j = 0; j < 8; ++j) {
    int d = j8 * 8 + j;
    float ang = (float)s * exp2fast((float)d * (-13.287712379549449f / 64.0f));
    float sn, cs;
    __sincosf(ang, &sn, &cs);
    float a = bf2f(x1[j]), bb2 = bf2f(x2[j]);
    y1[j] = f2bf(a * cs - bb2 * sn);
    y2[j] = f2bf(a * sn + bb2 * cs);
  }
  *(bf16x8*)base = y1;
  *(bf16x8*)(base + 64) = y2;
}

// ============ flash attention v6: barrier-free wave-split-K ===============
// grid (32, 16, 2); block = 64 q-rows, 4 waves; wave w owns kt tiles
// (32 keys) with kt % 4 == w, private LDS K/V/P; partial O/l additive
// (no-max softmax); single end-of-kernel cross-wave LDS reduction.
__global__ __launch_bounds__(256, 2) void flash_kernel(
    const short* __restrict__ q, const short* __restrict__ k,
    const short* __restrict__ vt, const float* __restrict__ mb,
    short* __restrict__ out) {
  __shared__ __align__(16) char smem[81920];
  const int qx = 31 - (int)blockIdx.x;  // heavy blocks first
  const int h = blockIdx.y, b = blockIdx.z;
  const int tid = threadIdx.x;
  const int w = tid >> 6, lane = tid & 63;
  const int lm = lane & 15, q4 = lane >> 4;

  short* Kb = (short*)(smem + w * 20480);          // [32 k][128 d] swz ^(r&7)
  short* Vb = (short*)(smem + w * 20480 + 8192);   // [128 d][32 k]
  char*  Pb = smem + w * 20480 + 16384;            // [64 q][32 k] bf16 swz f(q)

  // ---- Q fragments (pre-roped, pre-scaled): B[n=q][k=d] ----
  bf16x8 qf[4][4];
  const short* qbase = q + ((size_t)b * SS + qx * 64) * (NHEADS * DKV) + h * DKV;
#pragma unroll
  for (int ni = 0; ni < 4; ++ni)
#pragma unroll
    for (int ks = 0; ks < 4; ++ks)
      qf[ni][ks] = *(const bf16x8*)(qbase + (size_t)(ni * 16 + lm) * (NHEADS * DKV) +
                                    ks * 32 + q4 * 8);

  bf16x8 onesb;
#pragma unroll
  for (int j = 0; j < 8; ++j) onesb[j] = (short)0x3F80;

  f32x4 O[8][4];  // [vi d-tile][ni q-tile]; C: row=q(q4*4+reg), col=d(lm)
  f32x4 Ol[4];
#pragma unroll
  for (int vi = 0; vi < 8; ++vi)
#pragma unroll
    for (int ni = 0; ni < 4; ++ni) O[vi][ni] = (f32x4){0.f, 0.f, 0.f, 0.f};
#pragma unroll
  for (int ni = 0; ni < 4; ++ni) Ol[ni] = (f32x4){0.f, 0.f, 0.f, 0.f};

  const int fq = (lm ^ (lm >> 2)) & 3;
  const int ktmax = 2 * qx + 2;

  for (int kt = w; kt < ktmax; kt += 4) {
    // ---- stage K [32][128]: 8 insts, row = i*4+(lane>>4), swz ^(r&7) ----
#pragma unroll
    for (int i = 0; i < 8; ++i) {
      int r = i * 4 + (lane >> 4);
      int cl = (lane & 15) ^ (r & 7);
      async16(k + ((size_t)b * SS + kt * 32 + r) * DKV + cl * 8, Kb + i * 512);
    }
    // ---- stage V^T [128][32]: 8 insts, row = i*16+(lane>>2), no swz ----
#pragma unroll
    for (int i = 0; i < 8; ++i) {
      int r = i * 16 + (lane >> 2);
      async16(vt + ((size_t)b * DKV + r) * SS + kt * 32 + (lane & 3) * 8,
              Vb + i * 512);
    }
    f32x4 mb0 = *(const f32x4*)(mb + (size_t)b * SS + kt * 32 + q4 * 4);
    f32x4 mb1 = *(const f32x4*)(mb + (size_t)b * SS + kt * 32 + 16 + q4 * 4);
    wait_vm0();

    const bool diag = (kt >= 2 * qx);
#pragma unroll
    for (int mi = 0; mi < 2; ++mi) {
      f32x4 sacc[4];
#pragma unroll
      for (int ni = 0; ni < 4; ++ni) sacc[ni] = (f32x4){0.f, 0.f, 0.f, 0.f};
#pragma unroll
      for (int ks = 0; ks < 4; ++ks) {
        bf16x8 kf = *(const bf16x8*)&Kb[(mi * 16 + lm) * 128 +
                                        (((ks * 4 + q4) ^ (lm & 7)) << 3)];
#pragma unroll
        for (int ni = 0; ni < 4; ++ni)
          sacc[ni] = __builtin_amdgcn_mfma_f32_16x16x32_bf16(
              kf, qf[ni][ks], sacc[ni], 0, 0, 0);
      }
      f32x4 mbv = mi ? mb1 : mb0;
#pragma unroll
      for (int ni = 0; ni < 4; ++ni) {
        float pv[4];
#pragma unroll
        for (int reg = 0; reg < 4; ++reg) {
          float s = sacc[ni][reg] + mbv[reg];
          if (diag) {
            int kg = kt * 32 + mi * 16 + q4 * 4 + reg;
            int qg = qx * 64 + ni * 16 + lm;
            if (kg > qg) s = -1e30f;
          }
          pv[reg] = exp2fast(s);
        }
        int qr = ni * 16 + lm;
        int phys = (mi * 2 + (q4 >> 1)) ^ fq;
        uint2 pkd = {pk2bf(pv[0], pv[1]), pk2bf(pv[2], pv[3])};
        *(uint2*)(Pb + qr * 64 + phys * 16 + (q4 & 1) * 8) = pkd;
      }
    }

    // ---- O += P V ; Ol += P 1 ----
    bf16x8 pf[4];
#pragma unroll
    for (int ni = 0; ni < 4; ++ni) {
      pf[ni] = *(const bf16x8*)(Pb + (ni * 16 + lm) * 64 + ((q4 ^ fq) << 4));
      Ol[ni] = __builtin_amdgcn_mfma_f32_16x16x32_bf16(pf[ni], onesb, Ol[ni], 0, 0, 0);
    }
#pragma unroll
    for (int vi = 0; vi < 8; ++vi) {
      bf16x8 vf = *(const bf16x8*)&Vb[(vi * 16 + lm) * 32 + q4 * 8];
#pragma unroll
      for (int ni = 0; ni < 4; ++ni)
        O[vi][ni] = __builtin_amdgcn_mfma_f32_16x16x32_bf16(
            pf[ni], vf, O[vi][ni], 0, 0, 0);
    }
  }

  // ================= cross-wave additive reduction =================
  __syncthreads();  // loop buffers dead from here
  float* Wp = (float*)(smem + w * 17408);            // [64 q][68 d-half] f32
  float* Ls = (float*)(smem + 4 * 17408);            // [4][64] f32
  if (lm == 0) {
#pragma unroll
    for (int ni = 0; ni < 4; ++ni)
      *(f32x4*)&Ls[w * 64 + ni * 16 + q4 * 4] = Ol[ni];
  }
#pragma unroll
  for (int half = 0; half < 2; ++half) {
    if (half) __syncthreads();
    // write partial: O[vi][ni][reg] -> Wp[q = ni*16+q4*4+reg][dl = (vi%4)*16+lm]
#pragma unroll
    for (int v4 = 0; v4 < 4; ++v4) {
      int vi = half * 4 + v4;
#pragma unroll
      for (int ni = 0; ni < 4; ++ni)
#pragma unroll
        for (int reg = 0; reg < 4; ++reg)
          Wp[(ni * 16 + q4 * 4 + reg) * 68 + v4 * 16 + lm] = O[vi][ni][reg];
    }
    __syncthreads();
    // each wave sums q-rows [w*16, w*16+16): thread row = w*16+lm, d = q4*16+i*4
    int qr = w * 16 + lm;
    float lsum = Ls[qr] + Ls[64 + qr] + Ls[128 + qr] + Ls[192 + qr];
    float linv = 1.0f / lsum;
    f32x4 s0 = (f32x4){0.f, 0.f, 0.f, 0.f}, s1 = s0, s2 = s0, s3 = s0;
#pragma unroll
    for (int p = 0; p < 4; ++p) {
      const float* Pp = (const float*)(smem + p * 17408) + qr * 68 + q4 * 16;
      s0 += *(const f32x4*)(Pp + 0);
      s1 += *(const f32x4*)(Pp + 4);
      s2 += *(const f32x4*)(Pp + 8);
      s3 += *(const f32x4*)(Pp + 12);
    }
    size_t orow = ((size_t)b * SS + qx * 64 + qr) * (NHEADS * DKV) + h * DKV +
                  half * 64 + q4 * 16;
    uint4 o0 = {pk2bf(s0[0] * linv, s0[1] * linv), pk2bf(s0[2] * linv, s0[3] * linv),
                pk2bf(s1[0] * linv, s1[1] * linv), pk2bf(s1[2] * linv, s1[3] * linv)};
    uint4 o1 = {pk2bf(s2[0] * linv, s2[1] * linv), pk2bf(s2[2] * linv, s2[3] * linv),
                pk2bf(s3[0] * linv, s3[1] * linv), pk2bf(s3[2] * linv, s3[3] * linv)};
    *(uint4*)(out + orow) = o0;
    *(uint4*)(out + orow + 8) = o1;
  }
}

// ================= launch =================================================
extern "C" void kernel_launch(void* const* d_in, const int* in_sizes, int n_in,
                              void* d_out, int out_size, void* d_ws, size_t ws_size,
                              hipStream_t stream) {
  const float* q_in = (const float*)d_in[0];
  const float* k_in = (const float*)d_in[1];
  const float* v_in = (const float*)d_in[2];
  const unsigned char* mask = (const unsigned char*)d_in[3];
  const float* Wq = (const float*)d_in[4];
  const float* bq = (const float*)d_in[5];
  const float* Wk = (const float*)d_in[6];
  const float* bk = (const float*)d_in[7];
  const float* Wv = (const float*)d_in[8];
  const float* bv = (const float*)d_in[9];
  const float* Wo = (const float*)d_in[10];
  const float* bo = (const float*)d_in[11];

  const int M = BB * SS;  // 4096
  short* Wqt = (short*)d_ws;                   // [2048][2048]
  short* Wot = Wqt + (size_t)DD * DD;          // [2048][2048]
  short* Wkt = Wot + (size_t)DD * DD;          // [128][2048]
  short* Wvt = Wkt + (size_t)DKV * DD;         // [128][2048]
  short* qp  = Wvt + (size_t)DKV * DD;         // [4096][2048] bf16 (Q proj)
  short* kp  = qp + (size_t)M * DD;            // [4096][128] bf16 (roped K)
  short* vtb = kp + (size_t)M * DKV;           // [2][128][2048] bf16 (V^T)
  short* ap  = vtb + (size_t)BB * DKV * SS;    // [4096][2048] bf16 (attn out)
  float* mb = (float*)(ap + (size_t)M * DD);   // [2][2048] mask bias
  float* kpart = mb + (size_t)BB * SS;         // [4][4096][128]
  float* vpart = kpart + (size_t)SPLITK * M * DKV;

  transpose_w<<<dim3(DD / 32, DD / 32), 256, 0, stream>>>(Wq, Wqt, DD, DD, QSCL);
  transpose_w<<<dim3(DKV / 32, DD / 32), 256, 0, stream>>>(Wk, Wkt, DD, DKV, 1.0f);
  transpose_w<<<dim3(DKV / 32, DD / 32), 256, 0, stream>>>(Wv, Wvt, DD, DKV, 1.0f);
  transpose_w<<<dim3(DD / 32, DD / 32), 256, 0, stream>>>(Wo, Wot, DD, DD, 1.0f);
  mask_bias<<<BB * SS / 256, 256, 0, stream>>>(mask, mb);

  gemm_as<0><<<dim3(DD / 128, M / 128, 1), 256, 0, stream>>>(
      q_in, Wqt, bq, qp, M, DD, DD, DD, 1, QSCL);
  gemm_as<0><<<dim3(1, M / 128, SPLITK), 256, 0, stream>>>(
      k_in, Wkt, nullptr, kpart, M, DKV, DD, DD / SPLITK, 2, 1.0f);
  gemm_as<0><<<dim3(1, M / 128, SPLITK), 256, 0, stream>>>(
      v_in, Wvt, nullptr, vpart, M, DKV, DD, DD / SPLITK, 2, 1.0f);
  kv_reduce<<<M / 32, 256, 0, stream>>>(kpart, vpart, bk, bv, kp, vtb);
  rope_q<<<(BB * SS * NHEADS * 8) / 256, 256, 0, stream>>>(qp);

  flash_kernel<<<dim3(32, NHEADS, BB), 256, 0, stream>>>(qp, kp, vtb, mb, ap);

  gemm_as<1><<<dim3(DD / 128, M / 128, 1), 256, 0, stream>>>(
      ap, Wot, bo, d_out, M, DD, DD, DD, 0, 1.0f);
}

// Round 7
// 440.502 us; speedup vs baseline: 1.3583x; 1.3583x over previous
//
#include <hip/hip_runtime.h>

#define NHEADS 16
#define DKV 128
#define BB 2
#define SS 2048
#define DD 2048

typedef __attribute__((ext_vector_type(8))) short bf16x8;
typedef __attribute__((ext_vector_type(4))) short bf16x4;
typedef __attribute__((ext_vector_type(4))) float f32x4;

// scale 1/sqrt(128) * log2(e)  (we use exp2 instead of exp)
#define QSCL 0.12752775f

__device__ __forceinline__ short f2bf(float x) {
  unsigned u = __builtin_bit_cast(unsigned, x);
  unsigned r = (u + 0x7fffu + ((u >> 16) & 1u)) >> 16;  // RTNE
  return (short)(unsigned short)r;
}
__device__ __forceinline__ float bf2f(short s) {
  unsigned u = ((unsigned)(unsigned short)s) << 16;
  return __builtin_bit_cast(float, u);
}
__device__ __forceinline__ unsigned pk2bf(float a, float b) {
#if __has_builtin(__builtin_amdgcn_cvt_pk_bf16_f32)
  typedef __attribute__((ext_vector_type(2))) __bf16 bf2_t;
  bf2_t r = __builtin_amdgcn_cvt_pk_bf16_f32(a, b);
  return __builtin_bit_cast(unsigned, r);
#else
  unsigned ua = __builtin_bit_cast(unsigned, a);
  unsigned ub = __builtin_bit_cast(unsigned, b);
  return ((ua + 0x8000u) >> 16) | ((ub + 0x8000u) & 0xffff0000u);
#endif
}
__device__ __forceinline__ float exp2fast(float x) {
#if __has_builtin(__builtin_amdgcn_exp2f)
  return __builtin_amdgcn_exp2f(x);
#else
  return exp2f(x);
#endif
}

// async global->LDS, 16B/lane; lds dst = wave-uniform base + lane*16
__device__ __forceinline__ void async16(const void* g, void* l) {
  __builtin_amdgcn_global_load_lds(
      (__attribute__((address_space(1))) void*)g,
      (__attribute__((address_space(3))) void*)l, 16, 0, 0);
}

// ============ fp32 -> bf16 convert (q_in) =================================
__global__ __launch_bounds__(256) void cvt_q(const float* __restrict__ x,
                                             short* __restrict__ y) {
  int idx = blockIdx.x * 256 + threadIdx.x;
  int g = idx * 8;
  float4 a = *(const float4*)(x + g);
  float4 b = *(const float4*)(x + g + 4);
  uint4 o = {pk2bf(a.x, a.y), pk2bf(a.z, a.w), pk2bf(b.x, b.y), pk2bf(b.z, b.w)};
  *(uint4*)(y + g) = o;
}

// ============ weight transpose: W[K][N] fp32 -> Wt[N][K] bf16 * scale =====
__global__ __launch_bounds__(256) void transpose_w(
    const float* __restrict__ W, short* __restrict__ Wt, int K, int N,
    float scale) {
  __shared__ float T[32][33];
  const int nt = blockIdx.x * 32;
  const int kt = blockIdx.y * 32;
  const int tx = threadIdx.x & 31;
  const int ty = threadIdx.x >> 5;
#pragma unroll
  for (int i = 0; i < 4; ++i)
    T[ty + i * 8][tx] = W[(size_t)(kt + ty + i * 8) * N + nt + tx];
  __syncthreads();
#pragma unroll
  for (int i = 0; i < 4; ++i)
    Wt[(size_t)(nt + ty + i * 8) * K + kt + tx] = f2bf(T[tx][ty + i * 8] * scale);
}

// ============ mask bool -> float bias =====================================
__global__ void mask_bias(const unsigned char* __restrict__ m,
                          float* __restrict__ mb) {
  int i = blockIdx.x * 256 + threadIdx.x;
  mb[i] = m[i] ? -1e30f : 0.0f;
}

// ============ MFMA GEMM with async staging ================================
template <int AMODE>
__global__ __launch_bounds__(256) void gemm_as(
    const void* __restrict__ Ap, const short* __restrict__ Bt,
    const float* __restrict__ bias, void* __restrict__ Cp,
    int M, int N, int K, int KC, int cmode, float bscale) {
  __shared__ __align__(16) short As[128 * 32];
  __shared__ __align__(16) short Bs[128 * 32];
  const int tid = threadIdx.x;
  const int bm = blockIdx.y * 128;
  const int bn = blockIdx.x * 128;
  const int kz = blockIdx.z;
  const int w = tid >> 6, lane = tid & 63;
  const int lm = lane & 15, q4 = lane >> 4;
  const int m0 = (w & 1) * 64, n0 = (w >> 1) * 64;

  f32x4 acc[4][4];
#pragma unroll
  for (int mi = 0; mi < 4; ++mi)
#pragma unroll
    for (int ni = 0; ni < 4; ++ni) acc[mi][ni] = (f32x4){0.f, 0.f, 0.f, 0.f};

  const int kbeg = kz * KC;
  const int kend = kbeg + KC;

  for (int k0 = kbeg; k0 < kend; k0 += 32) {
    __syncthreads();
    if (AMODE == 1) {
      const short* Ab = (const short*)Ap;
#pragma unroll
      for (int i = 0; i < 2; ++i) {
        int rA = (w * 2 + i) * 16 + (lane >> 2);
        int cA = (lane & 3) ^ (rA & 3);
        async16(Ab + (size_t)(bm + rA) * K + k0 + cA * 8, &As[(w * 2 + i) * 512]);
      }
    } else {
      const float* Af = (const float*)Ap;
      float4 av[4];
#pragma unroll
      for (int i = 0; i < 4; ++i) {
        int qd = tid + i * 256;
        int r = qd >> 3, cq = qd & 7;
        av[i] = *(const float4*)(Af + (size_t)(bm + r) * K + k0 + cq * 4);
      }
#pragma unroll
      for (int i = 0; i < 4; ++i) {
        int qd = tid + i * 256;
        int r = qd >> 3, cq = qd & 7;
        int ch = cq >> 1, hf = cq & 1;
        int pc = ch ^ (r & 3);
        bf16x4 t = {f2bf(av[i].x), f2bf(av[i].y), f2bf(av[i].z), f2bf(av[i].w)};
        *(bf16x4*)&As[r * 32 + pc * 8 + hf * 4] = t;
      }
    }
#pragma unroll
    for (int i = 0; i < 2; ++i) {
      int rB = (w * 2 + i) * 16 + (lane >> 2);
      int cB = (lane & 3) ^ (rB & 3);
      async16(Bt + (size_t)(bn + rB) * K + k0 + cB * 8, &Bs[(w * 2 + i) * 512]);
    }
    __syncthreads();

    bf16x8 af[4], bf[4];
#pragma unroll
    for (int mi = 0; mi < 4; ++mi)
      af[mi] = *(const bf16x8*)&As[(m0 + mi * 16 + lm) * 32 + ((q4 ^ (lm & 3)) * 8)];
#pragma unroll
    for (int ni = 0; ni < 4; ++ni)
      bf[ni] = *(const bf16x8*)&Bs[(n0 + ni * 16 + lm) * 32 + ((q4 ^ (lm & 3)) * 8)];
#pragma unroll
    for (int mi = 0; mi < 4; ++mi)
#pragma unroll
      for (int ni = 0; ni < 4; ++ni)
        acc[mi][ni] = __builtin_amdgcn_mfma_f32_16x16x32_bf16(
            af[mi], bf[ni], acc[mi][ni], 0, 0, 0);
  }

  if (cmode == 2) {
    float* Cf = (float*)Cp + (size_t)kz * M * N;
#pragma unroll
    for (int mi = 0; mi < 4; ++mi)
#pragma unroll
      for (int ni = 0; ni < 4; ++ni)
#pragma unroll
        for (int reg = 0; reg < 4; ++reg)
          Cf[(size_t)(bm + m0 + mi * 16 + q4 * 4 + reg) * N +
             (bn + n0 + ni * 16 + lm)] = acc[mi][ni][reg];
  } else {
#pragma unroll
    for (int mi = 0; mi < 4; ++mi)
#pragma unroll
      for (int ni = 0; ni < 4; ++ni)
#pragma unroll
        for (int reg = 0; reg < 4; ++reg) {
          int rowg = bm + m0 + mi * 16 + q4 * 4 + reg;
          int colg = bn + n0 + ni * 16 + lm;
          float val = acc[mi][ni][reg] + bias[colg] * bscale;
          if (cmode == 0)
            ((float*)Cp)[(size_t)rowg * N + colg] = val;
          else
            ((short*)Cp)[(size_t)rowg * N + colg] = f2bf(val);
        }
  }
}

// ============ KV reduce + bias + K-RoPE + V-transpose =====================
#define SPLITK 4
__global__ __launch_bounds__(256) void kv_reduce(
    const float* __restrict__ kpart, const float* __restrict__ vpart,
    const float* __restrict__ bk, const float* __restrict__ bv,
    short* __restrict__ kp, short* __restrict__ vtb) {
  __shared__ float Kt[32][128];
  __shared__ short Vl[128][36];
  const int tid = threadIdx.x;
  const int r0 = blockIdx.x * 32;
#pragma unroll
  for (int i = 0; i < 16; ++i) {
    int e = tid + i * 256;
    int r = e >> 7, c = e & 127;
    float sk = 0.f, sv = 0.f;
#pragma unroll
    for (int z = 0; z < SPLITK; ++z) {
      sk += kpart[((size_t)z * 4096 + r0 + r) * 128 + c];
      sv += vpart[((size_t)z * 4096 + r0 + r) * 128 + c];
    }
    Kt[r][c] = sk + bk[c];
    Vl[c][r] = f2bf(sv + bv[c]);
  }
  __syncthreads();
#pragma unroll
  for (int i = 0; i < 8; ++i) {
    int e = tid + i * 256;
    int r = e >> 6, d = e & 63;
    float x1 = Kt[r][d], x2 = Kt[r][d + 64];
    float s = (float)((r0 + r) & (SS - 1));
    float ang = s * exp2fast((float)d * (-13.287712379549449f / 64.0f));
    float sn, cs;
    __sincosf(ang, &sn, &cs);
    kp[(size_t)(r0 + r) * 128 + d] = f2bf(x1 * cs - x2 * sn);
    kp[(size_t)(r0 + r) * 128 + d + 64] = f2bf(x1 * sn + x2 * cs);
  }
  const int b = r0 >> 11;
  const int j = tid >> 1, soff = (tid & 1) * 16;
  short* dst = vtb + ((size_t)b * 128 + j) * SS + (r0 & (SS - 1)) + soff;
#pragma unroll
  for (int t = 0; t < 2; ++t) {
    bf16x8 tmp;
#pragma unroll
    for (int u = 0; u < 8; ++u) tmp[u] = Vl[j][soff + t * 8 + u];
    *(bf16x8*)(dst + t * 8) = tmp;
  }
}

// ============ RoPE on projected Q (bf16, in place) ========================
__global__ __launch_bounds__(256) void rope_q(short* __restrict__ qp) {
  int idx = blockIdx.x * 256 + threadIdx.x;
  int j8 = idx & 7;
  int h = (idx >> 3) & (NHEADS - 1);
  int s = (idx >> 7) & (SS - 1);
  int b = idx >> 18;
  short* base = qp + (((size_t)b * SS + s) * NHEADS + h) * DKV + j8 * 8;
  bf16x8 x1 = *(bf16x8*)base;
  bf16x8 x2 = *(bf16x8*)(base + 64);
  bf16x8 y1, y2;
#pragma unroll
  for (int j = 0; j < 8; ++j) {
    int d = j8 * 8 + j;
    float ang = (float)s * exp2fast((float)d * (-13.287712379549449f / 64.0f));
    float sn, cs;
    __sincosf(ang, &sn, &cs);
    float a = bf2f(x1[j]), bb2 = bf2f(x2[j]);
    y1[j] = f2bf(a * cs - bb2 * sn);
    y2[j] = f2bf(a * sn + bb2 * cs);
  }
  *(bf16x8*)base = y1;
  *(bf16x8*)(base + 64) = y2;
}

// ============ flash attention v7: single-sync double-buffered pipeline ====
// grid (16, 16, 2), 256 thr = 4 waves; wave owns 32 q-rows (ni=2).
// K tiles 32 keys, double-buffered (2x8 KB). V staged in 64-key pairs,
// double-buffered (2x16 KB, 128B rows + ^(r&7) swizzle = conflict-free).
// Loop: sync (drains prefetch issued last iter) -> prefetch kt+1 -> compute.
// No-max softmax (additive), l via ones-B MFMA, LDS-transposed uint4 epilogue.
#define PSTR 40

__global__ __launch_bounds__(256, 2) void flash_kernel(
    const short* __restrict__ q, const short* __restrict__ k,
    const short* __restrict__ vt, const float* __restrict__ mb,
    short* __restrict__ out) {
  __shared__ __align__(16) short Kb[2][32 * 128];   // 16 KB
  __shared__ __align__(16) short Vb[2][128 * 64];   // 32 KB
  __shared__ __align__(16) short Ps[4][32 * PSTR];  // 10 KB
  const int qx = 15 - (int)blockIdx.x;  // heavy blocks first
  const int h = blockIdx.y, b = blockIdx.z;
  const int tid = threadIdx.x;
  const int w = tid >> 6, lane = tid & 63;
  const int lm = lane & 15, q4 = lane >> 4;
  const int qrow0 = qx * 128 + w * 32;

  // ---- Q fragments (pre-roped, pre-scaled): B[n=q][k=d], ni2 x ks4 ----
  bf16x8 qf[2][4];
#pragma unroll
  for (int ni = 0; ni < 2; ++ni)
#pragma unroll
    for (int ks = 0; ks < 4; ++ks)
      qf[ni][ks] = *(const bf16x8*)(q +
          ((size_t)b * SS + qrow0 + ni * 16 + lm) * (NHEADS * DKV) + h * DKV +
          ks * 32 + q4 * 8);

  bf16x8 onesb;
#pragma unroll
  for (int j = 0; j < 8; ++j) onesb[j] = (short)0x3F80;

  f32x4 O[8][2], Ol[2];
#pragma unroll
  for (int vi = 0; vi < 8; ++vi)
#pragma unroll
    for (int ni = 0; ni < 2; ++ni) O[vi][ni] = (f32x4){0.f, 0.f, 0.f, 0.f};
#pragma unroll
  for (int ni = 0; ni < 2; ++ni) Ol[ni] = (f32x4){0.f, 0.f, 0.f, 0.f};

  const int ktmax = 4 * qx + 4;
  const size_t kbase = (size_t)b * SS;

  // ---- prefetch helpers (inlined by hand) ----
  // stage K tile t -> Kb[t&1]
  // stage V pair {t,t+1} (t even) -> Vb[(t>>1)&1]
  {
    // K tile 0
#pragma unroll
    for (int i = 0; i < 2; ++i) {
      int r = (w * 2 + i) * 4 + (lane >> 4);
      int c = (lane & 15) ^ (r & 7);
      async16(k + (kbase + r) * DKV + c * 8, &Kb[0][(w * 2 + i) * 512]);
    }
    // V pair {0,1}
#pragma unroll
    for (int i = 0; i < 4; ++i) {
      int rV = (w * 4 + i) * 8 + (lane >> 3);
      int cV = (lane & 7) ^ (rV & 7);
      async16(vt + ((size_t)b * DKV + rV) * SS + cV * 8, &Vb[0][(w * 4 + i) * 512]);
    }
  }
  f32x4 mc0 = *(const f32x4*)(mb + kbase + q4 * 4);
  f32x4 mc1 = *(const f32x4*)(mb + kbase + 16 + q4 * 4);

  for (int kt = 0; kt < ktmax; ++kt) {
    __syncthreads();  // drains prefetch for tile kt (in flight since kt-1)

    f32x4 mn0, mn1;
    if (kt + 1 < ktmax) {
      const int t = kt + 1;
#pragma unroll
      for (int i = 0; i < 2; ++i) {
        int r = (w * 2 + i) * 4 + (lane >> 4);
        int c = (lane & 15) ^ (r & 7);
        async16(k + (kbase + (size_t)t * 32 + r) * DKV + c * 8,
                &Kb[t & 1][(w * 2 + i) * 512]);
      }
      if (kt & 1) {  // t even: stage V pair {t, t+1}
#pragma unroll
        for (int i = 0; i < 4; ++i) {
          int rV = (w * 4 + i) * 8 + (lane >> 3);
          int cV = (lane & 7) ^ (rV & 7);
          async16(vt + ((size_t)b * DKV + rV) * SS + (size_t)t * 32 + cV * 8,
                  &Vb[(t >> 1) & 1][(w * 4 + i) * 512]);
        }
      }
      mn0 = *(const f32x4*)(mb + kbase + (size_t)t * 32 + q4 * 4);
      mn1 = *(const f32x4*)(mb + kbase + (size_t)t * 32 + 16 + q4 * 4);
    }

    // ---- S^T = K (Q*scl)^T : mi2 x ks4 x ni2 ----
    const short* Kc = Kb[kt & 1];
    f32x4 sacc[2][2];
#pragma unroll
    for (int mi = 0; mi < 2; ++mi)
#pragma unroll
      for (int ni = 0; ni < 2; ++ni) sacc[mi][ni] = (f32x4){0.f, 0.f, 0.f, 0.f};
#pragma unroll
    for (int mi = 0; mi < 2; ++mi)
#pragma unroll
      for (int ks = 0; ks < 4; ++ks) {
        bf16x8 kf = *(const bf16x8*)&Kc[(mi * 16 + lm) * 128 +
                                        (((ks * 4 + q4) ^ (lm & 7)) << 3)];
#pragma unroll
        for (int ni = 0; ni < 2; ++ni)
          sacc[mi][ni] = __builtin_amdgcn_mfma_f32_16x16x32_bf16(
              kf, qf[ni][ks], sacc[mi][ni], 0, 0, 0);
      }

    // ---- exp2 + b64 P^T writes; causal only on last 4 tiles ----
    const bool diag = (kt >= 4 * qx);
#pragma unroll
    for (int mi = 0; mi < 2; ++mi) {
      f32x4 mbv = mi ? mc1 : mc0;
#pragma unroll
      for (int ni = 0; ni < 2; ++ni) {
        float pv[4];
#pragma unroll
        for (int reg = 0; reg < 4; ++reg) {
          float s = sacc[mi][ni][reg] + mbv[reg];
          if (diag) {
            int kg = kt * 32 + mi * 16 + q4 * 4 + reg;
            int qg = qrow0 + ni * 16 + lm;
            if (kg > qg) s = -1e30f;
          }
          pv[reg] = exp2fast(s);
        }
        uint2 pkd = {pk2bf(pv[0], pv[1]), pk2bf(pv[2], pv[3])};
        *(uint2*)&Ps[w][(ni * 16 + lm) * PSTR + mi * 16 + q4 * 4] = pkd;
      }
    }
    mc0 = mn0;
    mc1 = mn1;

    // ---- O += P V ; Ol += P 1  (32 keys = one K=32 step) ----
    const short* Vc = Vb[(kt >> 1) & 1];
    const int hf4 = (kt & 1) * 4;
    bf16x8 pf[2];
#pragma unroll
    for (int ni = 0; ni < 2; ++ni) {
      pf[ni] = *(const bf16x8*)&Ps[w][(ni * 16 + lm) * PSTR + q4 * 8];
      Ol[ni] = __builtin_amdgcn_mfma_f32_16x16x32_bf16(pf[ni], onesb, Ol[ni], 0, 0, 0);
    }
#pragma unroll
    for (int vi = 0; vi < 8; ++vi) {
      bf16x8 vf = *(const bf16x8*)&Vc[(vi * 16 + lm) * 64 +
                                      (((hf4 + q4) ^ (lm & 7)) << 3)];
#pragma unroll
      for (int ni = 0; ni < 2; ++ni)
        O[vi][ni] = __builtin_amdgcn_mfma_f32_16x16x32_bf16(
            pf[ni], vf, O[vi][ni], 0, 0, 0);
    }
  }

  // ---- epilogue: scale by 1/l in regs, LDS transpose, uint4 stores ----
  __syncthreads();  // all waves done with Vb; reuse as scratch
  float* Wr = (float*)&Vb[0][0] + w * 2048;  // 8 KB per wave
  float linv[2][4];
#pragma unroll
  for (int ni = 0; ni < 2; ++ni)
#pragma unroll
    for (int reg = 0; reg < 4; ++reg) linv[ni][reg] = 1.0f / Ol[ni][reg];

#pragma unroll
  for (int qd = 0; qd < 4; ++qd) {  // d-quarter = 32 dims (vi pair)
#pragma unroll
    for (int v2 = 0; v2 < 2; ++v2) {
      int vi = qd * 2 + v2;
#pragma unroll
      for (int ni = 0; ni < 2; ++ni)
#pragma unroll
        for (int reg = 0; reg < 4; ++reg)
          Wr[(ni * 16 + q4 * 4 + reg) * 34 + v2 * 16 + lm] =
              O[vi][ni][reg] * linv[ni][reg];
    }
    // read back: lane -> row r=lane&31, d-half16 = lane>>5
    int r = lane & 31, hh = lane >> 5;
    f32x4 t0 = *(const f32x4*)&Wr[r * 34 + hh * 16];
    f32x4 t1 = *(const f32x4*)&Wr[r * 34 + hh * 16 + 4];
    f32x4 t2 = *(const f32x4*)&Wr[r * 34 + hh * 16 + 8];
    f32x4 t3 = *(const f32x4*)&Wr[r * 34 + hh * 16 + 12];
    size_t oaddr = ((size_t)b * SS + qx * 128 + w * 32 + r) * (NHEADS * DKV) +
                   h * DKV + qd * 32 + hh * 16;
    uint4 o0 = {pk2bf(t0[0], t0[1]), pk2bf(t0[2], t0[3]),
                pk2bf(t1[0], t1[1]), pk2bf(t1[2], t1[3])};
    uint4 o1 = {pk2bf(t2[0], t2[1]), pk2bf(t2[2], t2[3]),
                pk2bf(t3[0], t3[1]), pk2bf(t3[2], t3[3])};
    *(uint4*)(out + oaddr) = o0;
    *(uint4*)(out + oaddr + 8) = o1;
  }
}

// ================= launch =================================================
extern "C" void kernel_launch(void* const* d_in, const int* in_sizes, int n_in,
                              void* d_out, int out_size, void* d_ws, size_t ws_size,
                              hipStream_t stream) {
  const float* q_in = (const float*)d_in[0];
  const float* k_in = (const float*)d_in[1];
  const float* v_in = (const float*)d_in[2];
  const unsigned char* mask = (const unsigned char*)d_in[3];
  const float* Wq = (const float*)d_in[4];
  const float* bq = (const float*)d_in[5];
  const float* Wk = (const float*)d_in[6];
  const float* bk = (const float*)d_in[7];
  const float* Wv = (const float*)d_in[8];
  const float* bv = (const float*)d_in[9];
  const float* Wo = (const float*)d_in[10];
  const float* bo = (const float*)d_in[11];

  const int M = BB * SS;  // 4096
  short* Wqt = (short*)d_ws;                   // [2048][2048]
  short* Wot = Wqt + (size_t)DD * DD;          // [2048][2048]
  short* Wkt = Wot + (size_t)DD * DD;          // [128][2048]
  short* Wvt = Wkt + (size_t)DKV * DD;         // [128][2048]
  short* qb  = Wvt + (size_t)DKV * DD;         // [4096][2048] bf16 (input)
  short* qp  = qb + (size_t)M * DD;            // [4096][2048] bf16 (Q proj)
  short* kp  = qp + (size_t)M * DD;            // [4096][128] bf16 (roped K)
  short* vtb = kp + (size_t)M * DKV;           // [2][128][2048] bf16 (V^T)
  float* mb  = (float*)(vtb + (size_t)BB * DKV * SS);  // [2][2048]
  float* kpart = mb + (size_t)BB * SS;         // [4][4096][128]
  float* vpart = kpart + (size_t)SPLITK * M * DKV;
  short* ap = qb;  // alias: qb dead after Q-proj; flash output reuses it

  cvt_q<<<M * DD / (8 * 256), 256, 0, stream>>>(q_in, qb);
  transpose_w<<<dim3(DD / 32, DD / 32), 256, 0, stream>>>(Wq, Wqt, DD, DD, QSCL);
  transpose_w<<<dim3(DKV / 32, DD / 32), 256, 0, stream>>>(Wk, Wkt, DD, DKV, 1.0f);
  transpose_w<<<dim3(DKV / 32, DD / 32), 256, 0, stream>>>(Wv, Wvt, DD, DKV, 1.0f);
  transpose_w<<<dim3(DD / 32, DD / 32), 256, 0, stream>>>(Wo, Wot, DD, DD, 1.0f);
  mask_bias<<<BB * SS / 256, 256, 0, stream>>>(mask, mb);

  gemm_as<1><<<dim3(DD / 128, M / 128, 1), 256, 0, stream>>>(
      qb, Wqt, bq, qp, M, DD, DD, DD, 1, QSCL);
  gemm_as<0><<<dim3(1, M / 128, SPLITK), 256, 0, stream>>>(
      k_in, Wkt, nullptr, kpart, M, DKV, DD, DD / SPLITK, 2, 1.0f);
  gemm_as<0><<<dim3(1, M / 128, SPLITK), 256, 0, stream>>>(
      v_in, Wvt, nullptr, vpart, M, DKV, DD, DD / SPLITK, 2, 1.0f);
  kv_reduce<<<M / 32, 256, 0, stream>>>(kpart, vpart, bk, bv, kp, vtb);
  rope_q<<<(BB * SS * NHEADS * 8) / 256, 256, 0, stream>>>(qp);

  flash_kernel<<<dim3(16, NHEADS, BB), 256, 0, stream>>>(qp, kp, vtb, mb, ap);

  gemm_as<1><<<dim3(DD / 128, M / 128, 1), 256, 0, stream>>>(
      ap, Wot, bo, d_out, M, DD, DD, DD, 0, 1.0f);
}